// Round 8
// baseline (283.683 us; speedup 1.0000x reference)
//
#include <hip/hip_runtime.h>
#include <cstdint>
#include <cstddef>

// GIN: B=32, N=1024, FIN=128, H1=64, H2=32, OUT=10. adj binary, ~1% dense.
// Round-8 (R7 was neutral vs R4 -> gather locality/CSR size weren't the cost):
//  - NO nontemporal on adj: if harness order is poison-ws THEN restore-inputs,
//    adj is L3-resident and NT was forcing a cold HBM stream (R5's "NT is
//    protective" claim was never isolated -- testing it now).
//  - Gathers fully unrolled to FIXED trip count (CAP=32): all 64 (gathA) /
//    32 (gathB) loads per wave are independent -> one latency epoch instead
//    of 3-4 round-serialized ones. Masked slots load row 0 (L1 hit, ~free).
//  - scanproj scan path: 2 rows/wave, all 8 row-loads issued upfront.
//  - Kept: CAP=32, XCD swizzles, LDS weights, no fences, separate k_fin.

#define CAP 32

typedef float v4f __attribute__((ext_vector_type(4)));

__device__ __forceinline__ float rl(float x, int l) {   // UNIFORM lane bcast only
  return __int_as_float(__builtin_amdgcn_readlane(__float_as_int(x), l));
}

// ---------------- fused: proj (u = x@W1a) + scan (adj -> CSR) ----------------
__global__ __launch_bounds__(256) void k_scanproj(
    const float* __restrict__ x, const float* __restrict__ W1a,
    float* __restrict__ u,
    const float* __restrict__ adj, int* __restrict__ nbr,
    int* __restrict__ deg) {
  int lane = threadIdx.x & 63;
  int wid  = threadIdx.x >> 6;
  if (blockIdx.x < 1024) {
    // ---- proj: u = x @ W1a, 8 rows/wave; W1a via L1 (exactly 32 KB) ----
    int p = blockIdx.x;                            // lands on XCD p%8
    int xcd = p & 7, q = p >> 3;                   // q in [0,128)
    int b = xcd + 8 * (q & 3);                     // batch b on XCD b%8
    int chunk = q >> 2;                            // [0,32): 32 rows each
    int row0 = b * 1024 + chunk * 32 + wid * 8;
    row0 = __builtin_amdgcn_readfirstlane(row0);
    const float* xr = x + (size_t)row0 * 128;
    float acc[8] = {0, 0, 0, 0, 0, 0, 0, 0};
    for (int kc = 0; kc < 32; ++kc) {
      v4f xv[8];
      #pragma unroll
      for (int r = 0; r < 8; ++r)
        xv[r] = *(const v4f*)(xr + r * 128 + kc * 4);
      #pragma unroll
      for (int j = 0; j < 4; ++j) {
        float w = W1a[(kc * 4 + j) * 64 + lane];
        #pragma unroll
        for (int r = 0; r < 8; ++r)
          acc[r] = fmaf(xv[r][j], w, acc[r]);
      }
    }
    #pragma unroll
    for (int r = 0; r < 8; ++r)
      u[(size_t)(row0 + r) * 64 + lane] = acc[r];
  } else {
    // ---- scan: 2 rows/wave (8 KB), all loads upfront, cached (L3-hot?) ----
    int s = blockIdx.x - 1024;                     // [0,4096), XCD s%8
    int xcd = s & 7, q = s >> 3;                   // q in [0,512)
    int b = xcd + 8 * (q & 3);
    int chunk = q >> 2;                            // [0,128): 8 rows each
    int node0 = b * 1024 + chunk * 8 + wid * 2;
    const v4f* arow = (const v4f*)(adj + (size_t)node0 * 1024);
    v4f a[8];
    #pragma unroll
    for (int c = 0; c < 8; ++c)
      a[c] = arow[c * 64 + lane];                  // rows node0, node0+1
    #pragma unroll
    for (int rrow = 0; rrow < 2; ++rrow) {
      int node = node0 + rrow;
      int* outp = nbr + node * CAP;
      int cnt = 0;
      #pragma unroll
      for (int c = 0; c < 4; ++c) {
        #pragma unroll
        for (int comp = 0; comp < 4; ++comp) {
          bool hit = (a[rrow * 4 + c][comp] != 0.0f);
          unsigned long long m = __ballot(hit);
          if (hit) {
            int below = __builtin_amdgcn_mbcnt_hi(
                (unsigned)(m >> 32),
                __builtin_amdgcn_mbcnt_lo((unsigned)m, 0));
            int pos = cnt + below;
            if (pos < CAP) outp[pos] = ((c * 64 + lane) << 2) + comp;
          }
          cnt += __popcll(m);
        }
      }
      if (lane == 0) deg[node] = cnt < CAP ? cnt : CAP;
    }
  }
}

// ---------------- layer A: gather u via CSR + MLP -> v ----------------
// Fixed 4x8 fully-unrolled gather: 64 independent loads in flight per wave.
__global__ __launch_bounds__(256, 4) void k_gathA(
    const float* __restrict__ u, const int* __restrict__ nbr,
    const int* __restrict__ deg, const float* __restrict__ mask,
    const float* __restrict__ b1a, const float* __restrict__ W2a,
    const float* __restrict__ b2a, const float* __restrict__ W1b,
    float* __restrict__ v) {
  __shared__ float sW2[64 * 64];    // 16 KB
  __shared__ float sW1b[64 * 32];   // 8 KB
  for (int t = threadIdx.x; t < 64 * 64; t += 256) sW2[t] = W2a[t];
  for (int t = threadIdx.x; t < 64 * 32; t += 256) sW1b[t] = W1b[t];
  __syncthreads();
  int lane = threadIdx.x & 63;
  int f = lane & 31, hh = lane >> 5;
  float ba1 = b1a[lane], ba2 = b2a[lane];
  int i = blockIdx.x, wid = threadIdx.x >> 6;
  int xcd = i & 7, j = i >> 3;
  int b = xcd + 8 * (j & 3);
  int w = j >> 2;                                  // 0..127
  int n0 = b * 1024 + w * 8 + wid * 2, n1 = n0 + 1;
  const float* ub = u + (size_t)b * 1024 * 64;
  int d0 = deg[n0], d1 = deg[n1];
  int nl = nbr[n0 * CAP + lane];                   // both lists in one load
  float s0[8] = {0,0,0,0,0,0,0,0}, s1[8] = {0,0,0,0,0,0,0,0};
  #pragma unroll
  for (int r = 0; r < 4; ++r) {
    #pragma unroll
    for (int i2 = 0; i2 < 8; ++i2) {
      int t = r * 8 + i2;                          // wave-uniform, < 32
      int j0 = __builtin_amdgcn_readlane(nl, t);
      int j1 = __builtin_amdgcn_readlane(nl, 32 + t);
      bool ok0 = t < d0, ok1 = t < d1;
      j0 = ok0 ? j0 : 0;  j1 = ok1 ? j1 : 0;       // masked slot -> row 0 (L1)
      float v0 = ub[j0 * 64 + lane];
      float v1 = ub[j1 * 64 + lane];
      s0[i2] += ok0 ? v0 : 0.0f;
      s1[i2] += ok1 ? v1 : 0.0f;
    }
  }
  float acc0 = ub[(n0 & 1023) * 64 + lane]
             + (((s0[0]+s0[1])+(s0[2]+s0[3]))+((s0[4]+s0[5])+(s0[6]+s0[7])));
  float acc1 = ub[(n1 & 1023) * 64 + lane]
             + (((s1[0]+s1[1])+(s1[2]+s1[3]))+((s1[4]+s1[5])+(s1[6]+s1[7])));
  float r0 = fmaxf(acc0 + ba1, 0.0f);
  float r1 = fmaxf(acc1 + ba1, 0.0f);
  float a0=0,a1=0,a2=0,a3=0, c0=0,c1=0,c2=0,c3=0;
  #pragma unroll
  for (int k = 0; k < 64; k += 4) {                // k wave-uniform -> rl OK
    float w0 = sW2[(k    ) * 64 + lane];
    float w1 = sW2[(k + 1) * 64 + lane];
    float w2 = sW2[(k + 2) * 64 + lane];
    float w3 = sW2[(k + 3) * 64 + lane];
    a0 = fmaf(rl(r0, k    ), w0, a0);  c0 = fmaf(rl(r1, k    ), w0, c0);
    a1 = fmaf(rl(r0, k + 1), w1, a1);  c1 = fmaf(rl(r1, k + 1), w1, c1);
    a2 = fmaf(rl(r0, k + 2), w2, a2);  c2 = fmaf(rl(r1, k + 2), w2, c2);
    a3 = fmaf(rl(r0, k + 3), w3, a3);  c3 = fmaf(rl(r1, k + 3), w3, c3);
  }
  float h20 = (ba2 + ((a0 + a1) + (a2 + a3))) * mask[n0];
  float h21 = (ba2 + ((c0 + c1) + (c2 + c3))) * mask[n1];
  float p00=0,p01=0, p10=0,p11=0;
  #pragma unroll
  for (int k0 = 0; k0 < 32; k0 += 2) {             // divergent idx -> __shfl
    float w0 = sW1b[(hh * 32 + k0    ) * 32 + f];
    float w1 = sW1b[(hh * 32 + k0 + 1) * 32 + f];
    p00 = fmaf(__shfl(h20, hh * 32 + k0    ), w0, p00);
    p01 = fmaf(__shfl(h20, hh * 32 + k0 + 1), w1, p01);
    p10 = fmaf(__shfl(h21, hh * 32 + k0    ), w0, p10);
    p11 = fmaf(__shfl(h21, hh * 32 + k0 + 1), w1, p11);
  }
  float vp0 = p00 + p01;  vp0 += __shfl_xor(vp0, 32);
  float vp1 = p10 + p11;  vp1 += __shfl_xor(vp1, 32);
  if (hh == 0) {
    v[n0 * 32 + f] = vp0;
    v[n1 * 32 + f] = vp1;
  }
}

// ---------------- layer B: gather v via CSR + MLP + block-max -> pmax --------
// Fixed 2x8 fully-unrolled gather (halves alternate): 32 loads in flight.
__global__ __launch_bounds__(256, 4) void k_gathB(
    const float* __restrict__ v, const int* __restrict__ nbr,
    const int* __restrict__ deg, const float* __restrict__ mask,
    const float* __restrict__ b1b, const float* __restrict__ W2b,
    const float* __restrict__ b2b, float* __restrict__ pmax) {
  __shared__ float sW2b[32 * 32];   // 4 KB
  __shared__ float wred[4][32];
  for (int t = threadIdx.x; t < 32 * 32; t += 256) sW2b[t] = W2b[t];
  __syncthreads();
  int lane = threadIdx.x & 63;
  int f = lane & 31, hh = lane >> 5;
  float bb1 = b1b[f], bb2 = b2b[f];
  int i = blockIdx.x, wid = threadIdx.x >> 6;
  int xcd = i & 7, j = i >> 3;
  int b = xcd + 8 * (j & 3);
  int w = j >> 2;                                  // 0..127
  int n0 = b * 1024 + w * 8 + wid * 2, n1 = n0 + 1;
  const float* vb = v + (size_t)b * 1024 * 32;
  int d0 = deg[n0], d1 = deg[n1];
  int nl = nbr[n0 * CAP + lane];
  float s0[8] = {0,0,0,0,0,0,0,0}, s1[8] = {0,0,0,0,0,0,0,0};
  #pragma unroll
  for (int r = 0; r < 2; ++r) {
    #pragma unroll
    for (int i2 = 0; i2 < 8; ++i2) {
      int t = r * 16 + (i2 << 1) + hh;             // covers 0..31, half-split
      int j0 = __shfl(nl, t);
      int j1 = __shfl(nl, 32 + t);
      bool ok0 = t < d0, ok1 = t < d1;
      j0 = ok0 ? j0 : 0;  j1 = ok1 ? j1 : 0;
      float v0 = vb[j0 * 32 + f];
      float v1 = vb[j1 * 32 + f];
      s0[i2] += ok0 ? v0 : 0.0f;
      s1[i2] += ok1 ? v1 : 0.0f;
    }
  }
  float acc0 = ((s0[0]+s0[1])+(s0[2]+s0[3]))+((s0[4]+s0[5])+(s0[6]+s0[7]));
  float acc1 = ((s1[0]+s1[1])+(s1[2]+s1[3]))+((s1[4]+s1[5])+(s1[6]+s1[7]));
  acc0 += __shfl_xor(acc0, 32);
  acc1 += __shfl_xor(acc1, 32);
  float r0 = fmaxf(vb[(n0 & 1023) * 32 + f] + acc0 + bb1, 0.0f);
  float r1 = fmaxf(vb[(n1 & 1023) * 32 + f] + acc1 + bb1, 0.0f);
  float a0=0,a1=0,a2=0,a3=0, c0=0,c1=0,c2=0,c3=0;
  #pragma unroll
  for (int k = 0; k < 32; k += 4) {                // uniform rl
    float w0 = sW2b[(k    ) * 32 + f];
    float w1 = sW2b[(k + 1) * 32 + f];
    float w2 = sW2b[(k + 2) * 32 + f];
    float w3 = sW2b[(k + 3) * 32 + f];
    a0 = fmaf(rl(r0, k    ), w0, a0);  c0 = fmaf(rl(r1, k    ), w0, c0);
    a1 = fmaf(rl(r0, k + 1), w1, a1);  c1 = fmaf(rl(r1, k + 1), w1, c1);
    a2 = fmaf(rl(r0, k + 2), w2, a2);  c2 = fmaf(rl(r1, k + 2), w2, c2);
    a3 = fmaf(rl(r0, k + 3), w3, a3);  c3 = fmaf(rl(r1, k + 3), w3, c3);
  }
  float o0 = (bb2 + ((a0 + a1) + (a2 + a3))) * mask[n0];
  float o1 = (bb2 + ((c0 + c1) + (c2 + c3))) * mask[n1];
  float m = fmaxf(o0, o1);                         // halves hold same value
  if (hh == 0) wred[wid][f] = m;
  __syncthreads();
  if (threadIdx.x < 32) {
    float mm = fmaxf(fmaxf(wred[0][threadIdx.x], wred[1][threadIdx.x]),
                     fmaxf(wred[2][threadIdx.x], wred[3][threadIdx.x]));
    pmax[((b << 7) + w) * 32 + threadIdx.x] = mm;
  }
}

// ---------------- final: g = max_w pmax ; out = g@Wfc + bfc ----------------
__global__ __launch_bounds__(1024) void k_fin(
    const float* __restrict__ pmax, const float* __restrict__ Wfc,
    const float* __restrict__ bfc, float* __restrict__ out) {
  __shared__ float red[32][33];
  __shared__ float g[32];
  int b = blockIdx.x;
  int f = threadIdx.x & 31, c = threadIdx.x >> 5;  // 32 chunks of 4 partials
  const float* pb = pmax + (size_t)b * 128 * 32;
  float m = -3.4e38f;
  #pragma unroll
  for (int q = 0; q < 4; ++q)
    m = fmaxf(m, pb[(c * 4 + q) * 32 + f]);
  red[c][f] = m;
  __syncthreads();
  if (c == 0) {
    float mm = red[0][f];
    #pragma unroll
    for (int k = 1; k < 32; ++k) mm = fmaxf(mm, red[k][f]);
    g[f] = mm;
  }
  __syncthreads();
  if (threadIdx.x < 10) {
    float o = bfc[threadIdx.x];
    #pragma unroll
    for (int k = 0; k < 32; ++k)
      o = fmaf(g[k], Wfc[k * 10 + threadIdx.x], o);
    out[b * 10 + threadIdx.x] = o;
  }
}

extern "C" void kernel_launch(void* const* d_in, const int* in_sizes, int n_in,
                              void* d_out, int out_size, void* d_ws, size_t ws_size,
                              hipStream_t stream) {
  const float* x    = (const float*)d_in[0];
  const float* adj  = (const float*)d_in[1];
  const float* mask = (const float*)d_in[2];
  const float* W1a  = (const float*)d_in[3];
  const float* b1a  = (const float*)d_in[4];
  const float* W2a  = (const float*)d_in[5];
  const float* b2a  = (const float*)d_in[6];
  const float* W1b  = (const float*)d_in[7];
  const float* b1b  = (const float*)d_in[8];
  const float* W2b  = (const float*)d_in[9];
  const float* b2b  = (const float*)d_in[10];
  const float* Wfc  = (const float*)d_in[11];
  const float* bfc  = (const float*)d_in[12];
  float* out = (float*)d_out;

  // ws: u[0,8M) v[8M,12M) nbr[12M,16M) deg[16M,+128K) pmax[21M,+512K)
  char* ws = (char*)d_ws;
  float* u    = (float*)(ws);
  float* v    = (float*)(ws + (8u << 20));
  int*   nbr  = (int*)  (ws + (12u << 20));
  int*   deg  = (int*)  (ws + (16u << 20));
  float* pmax = (float*)(ws + (21u << 20));

  hipLaunchKernelGGL(k_scanproj, dim3(5120), dim3(256), 0, stream,
                     x, W1a, u, adj, nbr, deg);
  hipLaunchKernelGGL(k_gathA,    dim3(4096), dim3(256), 0, stream,
                     u, nbr, deg, mask, b1a, W2a, b2a, W1b, v);
  hipLaunchKernelGGL(k_gathB,    dim3(4096), dim3(256), 0, stream,
                     v, nbr, deg, mask, b1b, W2b, b2b, pmax);
  hipLaunchKernelGGL(k_fin,      dim3(32),   dim3(1024), 0, stream,
                     pmax, Wfc, bfc, out);
}

// Round 9
// 274.698 us; speedup vs baseline: 1.0327x; 1.0327x over previous
//
#include <hip/hip_runtime.h>
#include <cstdint>
#include <cstddef>

// GIN: B=32, N=1024, FIN=128, H1=64, H2=32, OUT=10. adj binary, ~1% dense.
// Round-9 = consolidation to best-measured config (R4, 274 us) + proven-safe:
//  - R4 structure: scanproj (block-specialized, no LDS), consumer-side XCD
//    swizzle in gathers, gathB fuses block-max -> pmax, separate tiny k_fin.
//  - NT loads on adj (R8 removal cost ~5 us: adj is NOT L3-hot; the 512 MiB
//    ws poison cycles L3 before my kernels run).
//  - Dynamic gather rounds (R8's full unroll regressed slightly).
//  - CAP=32 (R5/R7 proved absmax 0), one 128 B nbr load serves 2 nodes.
//  - NEW: deg/nbr/self-term loads issued BEFORE LDS weight staging +
//    __syncthreads, hiding their latency under the staging barrier.

#define CAP 32

typedef float v4f __attribute__((ext_vector_type(4)));

__device__ __forceinline__ float rl(float x, int l) {   // UNIFORM lane bcast only
  return __int_as_float(__builtin_amdgcn_readlane(__float_as_int(x), l));
}

// ---------------- fused: proj (u = x@W1a) + scan (adj -> CSR) ----------------
// NO __shared__ in this kernel: scan occupancy must not pay for it (R3->R4 win).
__global__ __launch_bounds__(256) void k_scanproj(
    const float* __restrict__ x, const float* __restrict__ W1a,
    float* __restrict__ u,
    const float* __restrict__ adj, int* __restrict__ nbr,
    int* __restrict__ deg) {
  int lane = threadIdx.x & 63;
  int wid  = threadIdx.x >> 6;
  if (blockIdx.x < 1024) {
    // ---- proj: u = x @ W1a, 8 rows/wave; W1a via L1 (exactly 32 KB) ----
    int row0 = (blockIdx.x * 4 + wid) * 8;
    row0 = __builtin_amdgcn_readfirstlane(row0);
    const float* xr = x + (size_t)row0 * 128;
    float acc[8] = {0, 0, 0, 0, 0, 0, 0, 0};
    for (int kc = 0; kc < 32; ++kc) {
      v4f xv[8];
      #pragma unroll
      for (int r = 0; r < 8; ++r)
        xv[r] = *(const v4f*)(xr + r * 128 + kc * 4);
      #pragma unroll
      for (int j = 0; j < 4; ++j) {
        float w = W1a[(kc * 4 + j) * 64 + lane];
        #pragma unroll
        for (int r = 0; r < 8; ++r)
          acc[r] = fmaf(xv[r][j], w, acc[r]);
      }
    }
    #pragma unroll
    for (int r = 0; r < 8; ++r)
      u[(size_t)(row0 + r) * 64 + lane] = acc[r];
  } else {
    // ---- scan: one wave per 4 KB adj row, NT stream, lane-parallel extract --
    int node = (blockIdx.x - 1024) * 4 + wid;      // 8192 blocks -> 32768 rows
    const v4f* arow = (const v4f*)(adj + (size_t)node * 1024);
    int* outp = nbr + node * CAP;
    v4f a[4];
    #pragma unroll
    for (int c = 0; c < 4; ++c)
      a[c] = __builtin_nontemporal_load(arow + c * 64 + lane);
    int cnt = 0;
    #pragma unroll
    for (int c = 0; c < 4; ++c) {
      #pragma unroll
      for (int comp = 0; comp < 4; ++comp) {
        bool hit = (a[c][comp] != 0.0f);
        unsigned long long m = __ballot(hit);
        if (hit) {
          int below = __builtin_amdgcn_mbcnt_hi(
              (unsigned)(m >> 32),
              __builtin_amdgcn_mbcnt_lo((unsigned)m, 0));
          int pos = cnt + below;
          if (pos < CAP) outp[pos] = ((c * 64 + lane) << 2) + comp;
        }
        cnt += __popcll(m);
      }
    }
    if (lane == 0) deg[node] = cnt < CAP ? cnt : CAP;
  }
}

// ---------------- layer A: gather u via CSR + MLP -> v ----------------
// Consumer XCD swizzle (R4). CSR/self loads issued BEFORE staging barrier.
__global__ __launch_bounds__(256) void k_gathA(
    const float* __restrict__ u, const int* __restrict__ nbr,
    const int* __restrict__ deg, const float* __restrict__ mask,
    const float* __restrict__ b1a, const float* __restrict__ W2a,
    const float* __restrict__ b2a, const float* __restrict__ W1b,
    float* __restrict__ v) {
  __shared__ float sW2[64 * 64];    // 16 KB
  __shared__ float sW1b[64 * 32];   // 8 KB
  int lane = threadIdx.x & 63;
  int f = lane & 31, hh = lane >> 5;
  int i = blockIdx.x, wid = threadIdx.x >> 6;
  int xcd = i & 7, j = i >> 3;
  int b = xcd + 8 * (j & 3);
  int w = j >> 2;                                  // 0..127
  int n0 = b * 1024 + w * 8 + wid * 2, n1 = n0 + 1;
  const float* ub = u + (size_t)b * 1024 * 64;
  // early-issue: latency hides under the weight staging + barrier below
  int d0 = deg[n0], d1 = deg[n1];
  int nl = nbr[n0 * CAP + lane];                   // both lists in one load
  float self0 = ub[(n0 & 1023) * 64 + lane];
  float self1 = ub[(n1 & 1023) * 64 + lane];
  float ba1 = b1a[lane], ba2 = b2a[lane];
  float mk0 = mask[n0], mk1 = mask[n1];
  for (int t = threadIdx.x; t < 64 * 64; t += 256) sW2[t] = W2a[t];
  for (int t = threadIdx.x; t < 64 * 32; t += 256) sW1b[t] = W1b[t];
  __syncthreads();
  float s0[8] = {0,0,0,0,0,0,0,0}, s1[8] = {0,0,0,0,0,0,0,0};
  int dmax = d0 > d1 ? d0 : d1;
  int rounds = (dmax + 7) >> 3;
  for (int rr = 0; rr < rounds; ++rr) {
    int base = rr << 3;
    #pragma unroll
    for (int i2 = 0; i2 < 8; ++i2) {
      int t = base + i2;                           // wave-uniform, < 32
      int j0 = __builtin_amdgcn_readlane(nl, t);
      int j1 = __builtin_amdgcn_readlane(nl, 32 + t);
      bool ok0 = t < d0, ok1 = t < d1;
      j0 = ok0 ? j0 : 0;  j1 = ok1 ? j1 : 0;
      float v0 = ub[j0 * 64 + lane];               // 16 independent gathers
      float v1 = ub[j1 * 64 + lane];
      s0[i2] += ok0 ? v0 : 0.0f;
      s1[i2] += ok1 ? v1 : 0.0f;
    }
  }
  float acc0 = self0
             + (((s0[0]+s0[1])+(s0[2]+s0[3]))+((s0[4]+s0[5])+(s0[6]+s0[7])));
  float acc1 = self1
             + (((s1[0]+s1[1])+(s1[2]+s1[3]))+((s1[4]+s1[5])+(s1[6]+s1[7])));
  float r0 = fmaxf(acc0 + ba1, 0.0f);
  float r1 = fmaxf(acc1 + ba1, 0.0f);
  float a0=0,a1=0,a2=0,a3=0, c0=0,c1=0,c2=0,c3=0;
  #pragma unroll
  for (int k = 0; k < 64; k += 4) {                // k wave-uniform -> rl OK
    float w0 = sW2[(k    ) * 64 + lane];
    float w1 = sW2[(k + 1) * 64 + lane];
    float w2 = sW2[(k + 2) * 64 + lane];
    float w3 = sW2[(k + 3) * 64 + lane];
    a0 = fmaf(rl(r0, k    ), w0, a0);  c0 = fmaf(rl(r1, k    ), w0, c0);
    a1 = fmaf(rl(r0, k + 1), w1, a1);  c1 = fmaf(rl(r1, k + 1), w1, c1);
    a2 = fmaf(rl(r0, k + 2), w2, a2);  c2 = fmaf(rl(r1, k + 2), w2, c2);
    a3 = fmaf(rl(r0, k + 3), w3, a3);  c3 = fmaf(rl(r1, k + 3), w3, c3);
  }
  float h20 = (ba2 + ((a0 + a1) + (a2 + a3))) * mk0;
  float h21 = (ba2 + ((c0 + c1) + (c2 + c3))) * mk1;
  float p00=0,p01=0, p10=0,p11=0;
  #pragma unroll
  for (int k0 = 0; k0 < 32; k0 += 2) {             // divergent idx -> __shfl
    float w0 = sW1b[(hh * 32 + k0    ) * 32 + f];
    float w1 = sW1b[(hh * 32 + k0 + 1) * 32 + f];
    p00 = fmaf(__shfl(h20, hh * 32 + k0    ), w0, p00);
    p01 = fmaf(__shfl(h20, hh * 32 + k0 + 1), w1, p01);
    p10 = fmaf(__shfl(h21, hh * 32 + k0    ), w0, p10);
    p11 = fmaf(__shfl(h21, hh * 32 + k0 + 1), w1, p11);
  }
  float vp0 = p00 + p01;  vp0 += __shfl_xor(vp0, 32);
  float vp1 = p10 + p11;  vp1 += __shfl_xor(vp1, 32);
  if (hh == 0) {
    v[n0 * 32 + f] = vp0;
    v[n1 * 32 + f] = vp1;
  }
}

// ---------------- layer B: gather v via CSR + MLP + block-max -> pmax --------
__global__ __launch_bounds__(256) void k_gathB(
    const float* __restrict__ v, const int* __restrict__ nbr,
    const int* __restrict__ deg, const float* __restrict__ mask,
    const float* __restrict__ b1b, const float* __restrict__ W2b,
    const float* __restrict__ b2b, float* __restrict__ pmax) {
  __shared__ float sW2b[32 * 32];   // 4 KB
  __shared__ float wred[4][32];
  int lane = threadIdx.x & 63;
  int f = lane & 31, hh = lane >> 5;
  int i = blockIdx.x, wid = threadIdx.x >> 6;
  int xcd = i & 7, j = i >> 3;
  int b = xcd + 8 * (j & 3);
  int w = j >> 2;                                  // 0..127
  int n0 = b * 1024 + w * 8 + wid * 2, n1 = n0 + 1;
  const float* vb = v + (size_t)b * 1024 * 32;
  // early-issue before the staging barrier
  int d0 = deg[n0], d1 = deg[n1];
  int nl = nbr[n0 * CAP + lane];
  float self0 = vb[(n0 & 1023) * 32 + f];
  float self1 = vb[(n1 & 1023) * 32 + f];
  float bb1 = b1b[f], bb2 = b2b[f];
  float mk0 = mask[n0], mk1 = mask[n1];
  for (int t = threadIdx.x; t < 32 * 32; t += 256) sW2b[t] = W2b[t];
  __syncthreads();
  float s0[8] = {0,0,0,0,0,0,0,0}, s1[8] = {0,0,0,0,0,0,0,0};
  int dmax = d0 > d1 ? d0 : d1;
  int rounds = (dmax + 15) >> 4;
  for (int rr = 0; rr < rounds; ++rr) {
    int base = rr << 4;
    #pragma unroll
    for (int i2 = 0; i2 < 8; ++i2) {
      int t = base + (i2 << 1) + hh;               // halves alternate nbrs
      int j0 = __shfl(nl, t);
      int j1 = __shfl(nl, 32 + t);
      bool ok0 = t < d0, ok1 = t < d1;
      j0 = ok0 ? j0 : 0;  j1 = ok1 ? j1 : 0;
      float v0 = vb[j0 * 32 + f];
      float v1 = vb[j1 * 32 + f];
      s0[i2] += ok0 ? v0 : 0.0f;
      s1[i2] += ok1 ? v1 : 0.0f;
    }
  }
  float acc0 = ((s0[0]+s0[1])+(s0[2]+s0[3]))+((s0[4]+s0[5])+(s0[6]+s0[7]));
  float acc1 = ((s1[0]+s1[1])+(s1[2]+s1[3]))+((s1[4]+s1[5])+(s1[6]+s1[7]));
  acc0 += __shfl_xor(acc0, 32);
  acc1 += __shfl_xor(acc1, 32);
  float r0 = fmaxf(self0 + acc0 + bb1, 0.0f);
  float r1 = fmaxf(self1 + acc1 + bb1, 0.0f);
  float a0=0,a1=0,a2=0,a3=0, c0=0,c1=0,c2=0,c3=0;
  #pragma unroll
  for (int k = 0; k < 32; k += 4) {                // uniform rl
    float w0 = sW2b[(k    ) * 32 + f];
    float w1 = sW2b[(k + 1) * 32 + f];
    float w2 = sW2b[(k + 2) * 32 + f];
    float w3 = sW2b[(k + 3) * 32 + f];
    a0 = fmaf(rl(r0, k    ), w0, a0);  c0 = fmaf(rl(r1, k    ), w0, c0);
    a1 = fmaf(rl(r0, k + 1), w1, a1);  c1 = fmaf(rl(r1, k + 1), w1, c1);
    a2 = fmaf(rl(r0, k + 2), w2, a2);  c2 = fmaf(rl(r1, k + 2), w2, c2);
    a3 = fmaf(rl(r0, k + 3), w3, a3);  c3 = fmaf(rl(r1, k + 3), w3, c3);
  }
  float o0 = (bb2 + ((a0 + a1) + (a2 + a3))) * mk0;
  float o1 = (bb2 + ((c0 + c1) + (c2 + c3))) * mk1;
  float m = fmaxf(o0, o1);                         // halves hold same value
  if (hh == 0) wred[wid][f] = m;
  __syncthreads();
  if (threadIdx.x < 32) {
    float mm = fmaxf(fmaxf(wred[0][threadIdx.x], wred[1][threadIdx.x]),
                     fmaxf(wred[2][threadIdx.x], wred[3][threadIdx.x]));
    pmax[((b << 7) + w) * 32 + threadIdx.x] = mm;
  }
}

// ---------------- final: g = max_w pmax ; out = g@Wfc + bfc ----------------
__global__ __launch_bounds__(1024) void k_fin(
    const float* __restrict__ pmax, const float* __restrict__ Wfc,
    const float* __restrict__ bfc, float* __restrict__ out) {
  __shared__ float red[32][33];
  __shared__ float g[32];
  int b = blockIdx.x;
  int f = threadIdx.x & 31, c = threadIdx.x >> 5;  // 32 chunks of 4 partials
  const float* pb = pmax + (size_t)b * 128 * 32;
  float m = -3.4e38f;
  #pragma unroll
  for (int q = 0; q < 4; ++q)
    m = fmaxf(m, pb[(c * 4 + q) * 32 + f]);
  red[c][f] = m;
  __syncthreads();
  if (c == 0) {
    float mm = red[0][f];
    #pragma unroll
    for (int k = 1; k < 32; ++k) mm = fmaxf(mm, red[k][f]);
    g[f] = mm;
  }
  __syncthreads();
  if (threadIdx.x < 10) {
    float o = bfc[threadIdx.x];
    #pragma unroll
    for (int k = 0; k < 32; ++k)
      o = fmaf(g[k], Wfc[k * 10 + threadIdx.x], o);
    out[b * 10 + threadIdx.x] = o;
  }
}

extern "C" void kernel_launch(void* const* d_in, const int* in_sizes, int n_in,
                              void* d_out, int out_size, void* d_ws, size_t ws_size,
                              hipStream_t stream) {
  const float* x    = (const float*)d_in[0];
  const float* adj  = (const float*)d_in[1];
  const float* mask = (const float*)d_in[2];
  const float* W1a  = (const float*)d_in[3];
  const float* b1a  = (const float*)d_in[4];
  const float* W2a  = (const float*)d_in[5];
  const float* b2a  = (const float*)d_in[6];
  const float* W1b  = (const float*)d_in[7];
  const float* b1b  = (const float*)d_in[8];
  const float* W2b  = (const float*)d_in[9];
  const float* b2b  = (const float*)d_in[10];
  const float* Wfc  = (const float*)d_in[11];
  const float* bfc  = (const float*)d_in[12];
  float* out = (float*)d_out;

  // ws: u[0,8M) v[8M,12M) nbr[12M,16M) deg[16M,+128K) pmax[21M,+512K)
  char* ws = (char*)d_ws;
  float* u    = (float*)(ws);
  float* v    = (float*)(ws + (8u << 20));
  int*   nbr  = (int*)  (ws + (12u << 20));
  int*   deg  = (int*)  (ws + (16u << 20));
  float* pmax = (float*)(ws + (21u << 20));

  hipLaunchKernelGGL(k_scanproj, dim3(9216), dim3(256), 0, stream,
                     x, W1a, u, adj, nbr, deg);
  hipLaunchKernelGGL(k_gathA,    dim3(4096), dim3(256), 0, stream,
                     u, nbr, deg, mask, b1a, W2a, b2a, W1b, v);
  hipLaunchKernelGGL(k_gathB,    dim3(4096), dim3(256), 0, stream,
                     v, nbr, deg, mask, b1b, W2b, b2b, pmax);
  hipLaunchKernelGGL(k_fin,      dim3(32),   dim3(1024), 0, stream,
                     pmax, Wfc, bfc, out);
}